// Round 3
// baseline (378.695 us; speedup 1.0000x reference)
//
#include <hip/hip_runtime.h>

// y[b,s,f] = init[b] + FACTOR * cumsum_s(x)[b,s,f]
// B=1024, S=4096, F=11, fp32. Memory-bound streaming scan.
//
// R3 design: NO LDS data path.
//  - Each thread owns 4 consecutive timesteps (44 floats = 11 float4),
//    loaded directly from global at 176 B lane stride: a wave's 11 loads
//    cover one contiguous 11,264 B region -> every cache line fully
//    consumed, HBM traffic = compulsory.
//  - Per-thread local prefix (VALU), then 64-lane inclusive scan of the
//    11 per-thread totals via the classic 6-step DPP scan
//    (row_shr:1/2/4/8 + row_bcast:15/31) -- pure VALU, zero DS-pipe ops.
//  - Cross-wave combine via a 704 B waveTot LDS array, per-tile slots,
//    ONE barrier per tile. Cross-tile carry in registers.
//  - 1024 blocks x 256 threads, __launch_bounds__(256,4): 4 blocks/CU,
//    one dispatch round, 16 waves/CU for latency hiding.

#define BATCH    1024
#define SEQ      4096
#define FEAT     11
#define FACTOR   (-1.0f)

#define NTHREADS 256
#define TS       1024                    // timesteps per tile
#define NT       (SEQ / TS)              // 4 tiles
#define CPT      (TS / NTHREADS)         // 4 timesteps per thread
#define TILE_F4  (TS * FEAT / 4)         // 2816 float4 per tile
#define NWAVE    (NTHREADS / 64)         // 4

template <int CTRL, int RM, int BM, bool BC>
__device__ __forceinline__ float dpp_src(float v) {
    int r = __builtin_amdgcn_update_dpp(0, __float_as_int(v), CTRL, RM, BM, BC);
    return __int_as_float(r);
}

// 64-lane inclusive add-scan, all VALU (no DS pipe).
__device__ __forceinline__ float wave_iscan(float x) {
    x += dpp_src<0x111, 0xf, 0xf, true >(x);  // row_shr:1
    x += dpp_src<0x112, 0xf, 0xf, true >(x);  // row_shr:2
    x += dpp_src<0x114, 0xf, 0xf, true >(x);  // row_shr:4
    x += dpp_src<0x118, 0xf, 0xf, true >(x);  // row_shr:8  -> scan within rows of 16
    x += dpp_src<0x142, 0xa, 0xf, false>(x);  // row_bcast:15 -> rows 1,3
    x += dpp_src<0x143, 0xc, 0xf, false>(x);  // row_bcast:31 -> rows 2,3
    return x;
}

__global__ __launch_bounds__(NTHREADS, 4)
void rnn_scan_kernel(const float* __restrict__ x,
                     const float* __restrict__ init_state,
                     float* __restrict__ y) {
    __shared__ float waveTot[NT][NWAVE][FEAT];   // 704 B, per-tile slots

    const int b    = blockIdx.x;
    const int t    = threadIdx.x;
    const int lane = t & 63;
    const int wav  = t >> 6;

    const float4* __restrict__ xg =
        (const float4*)(x + (size_t)b * (SEQ * FEAT));
    float4* __restrict__ yg =
        (float4*)(y + (size_t)b * (SEQ * FEAT));
    const float init_v = init_state[b];

    float carry[FEAT];
#pragma unroll
    for (int f = 0; f < FEAT; ++f) carry[f] = 0.0f;

#pragma unroll
    for (int tile = 0; tile < NT; ++tile) {
        const int base = tile * TILE_F4 + FEAT * t;   // 11 float4 per thread

        // ---- direct global load: 44 floats = own 4 timesteps ----
        float4 q[FEAT];
#pragma unroll
        for (int k = 0; k < FEAT; ++k) q[k] = xg[base + k];

        float v[CPT * FEAT];
#pragma unroll
        for (int k = 0; k < FEAT; ++k) {
            v[4 * k + 0] = q[k].x; v[4 * k + 1] = q[k].y;
            v[4 * k + 2] = q[k].z; v[4 * k + 3] = q[k].w;
        }

        // ---- local inclusive prefix over own 4 steps, per feature ----
#pragma unroll
        for (int s = 1; s < CPT; ++s)
#pragma unroll
            for (int f = 0; f < FEAT; ++f)
                v[s * FEAT + f] += v[(s - 1) * FEAT + f];

        // ---- wave-level inclusive scan of per-thread totals (DPP/VALU) ----
        float inc[FEAT];
#pragma unroll
        for (int f = 0; f < FEAT; ++f)
            inc[f] = wave_iscan(v[(CPT - 1) * FEAT + f]);

        if (lane == 63) {
#pragma unroll
            for (int f = 0; f < FEAT; ++f) waveTot[tile][wav][f] = inc[f];
        }
        __syncthreads();   // one barrier/tile; per-tile slots -> no WAR

        // ---- offsets + epilogue ----
#pragma unroll
        for (int f = 0; f < FEAT; ++f) {
            float off = carry[f] + inc[f] - v[(CPT - 1) * FEAT + f]; // excl in wave
#pragma unroll
            for (int w = 0; w < NWAVE; ++w) {
                float wt = waveTot[tile][w][f];   // broadcast read
                if (w < wav) off += wt;           // preceding waves
                carry[f] += wt;                   // tile total -> next tile
            }
#pragma unroll
            for (int s = 0; s < CPT; ++s)
                v[s * FEAT + f] = init_v + FACTOR * (off + v[s * FEAT + f]);
        }

        // ---- direct global store, same per-lane layout ----
#pragma unroll
        for (int k = 0; k < FEAT; ++k) {
            float4 o;
            o.x = v[4 * k + 0]; o.y = v[4 * k + 1];
            o.z = v[4 * k + 2]; o.w = v[4 * k + 3];
            yg[base + k] = o;
        }
    }
}

extern "C" void kernel_launch(void* const* d_in, const int* in_sizes, int n_in,
                              void* d_out, int out_size, void* d_ws, size_t ws_size,
                              hipStream_t stream) {
    const float* x    = (const float*)d_in[0];
    const float* init = (const float*)d_in[1];
    float*       y    = (float*)d_out;
    rnn_scan_kernel<<<dim3(BATCH), dim3(NTHREADS), 0, stream>>>(x, init, y);
}

// Round 5
// 346.148 us; speedup vs baseline: 1.0940x; 1.0940x over previous
//
#include <hip/hip_runtime.h>

// y[b,s,f] = init[b] + FACTOR * cumsum_s(x)[b,s,f]
// B=1024, S=4096, F=11, fp32. Memory-bound.
//
// Two-pass chunked scan (no serial tile loop, no dispatch-order assumptions):
//   Kernel A: 8192 blocks (1024 rows x 8 chunks of 512 steps) -> per-chunk,
//             per-feature sums into d_ws (360 KB).
//   Kernel C: 8192 independent blocks; block (b,c) sums partials of chunks
//             < c for its row (<=7 scalar loads, unrolled/predicated), then
//             scans its own 512-step chunk: global_load_lds staging ->
//             float2 LDS transpose (bank stride 22, 2-way = free) -> DPP
//             wave scan (pure VALU) -> epilogue -> coalesced float4 store.

#define BATCH    1024
#define SEQ      4096
#define FEAT     11
#define FACTOR   (-1.0f)

#define NTHREADS 256
#define TS       512                     // timesteps per chunk
#define NC       (SEQ / TS)              // 8 chunks per row
#define NBLK     (BATCH * NC)            // 8192 blocks
#define TILE_F4  (TS * FEAT / 4)         // 1408 float4 per chunk
#define VLMAX    6                       // ceil(1408/256); i=5 only for t<128
#define NWAVE    (NTHREADS / 64)

template <int CTRL, int RM, int BM, bool BC>
__device__ __forceinline__ float dpp_src(float v) {
    int r = __builtin_amdgcn_update_dpp(0, __float_as_int(v), CTRL, RM, BM, BC);
    return __int_as_float(r);
}

// 64-lane inclusive add-scan, pure VALU (verified in R3).
__device__ __forceinline__ float wave_iscan(float x) {
    x += dpp_src<0x111, 0xf, 0xf, true >(x);  // row_shr:1
    x += dpp_src<0x112, 0xf, 0xf, true >(x);  // row_shr:2
    x += dpp_src<0x114, 0xf, 0xf, true >(x);  // row_shr:4
    x += dpp_src<0x118, 0xf, 0xf, true >(x);  // row_shr:8
    x += dpp_src<0x142, 0xa, 0xf, false>(x);  // row_bcast:15
    x += dpp_src<0x143, 0xc, 0xf, false>(x);  // row_bcast:31
    return x;
}

// async global->LDS, 16B per lane; LDS base taken from first active lane.
__device__ __forceinline__ void gload_lds16(const float4* g, float4* l) {
    __builtin_amdgcn_global_load_lds(
        (const __attribute__((address_space(1))) void*)g,
        (__attribute__((address_space(3))) void*)l, 16, 0, 0);
}

// ---------------- Kernel A: per-chunk per-feature sums ----------------
__global__ __launch_bounds__(NTHREADS, 8)
void partial_kernel(const float* __restrict__ x, float* __restrict__ partials) {
    __shared__ float4 tile[TILE_F4];          // 22,528 B
    __shared__ float  waveSum[NWAVE][FEAT];

    const int blk  = blockIdx.x;              // b*NC + c
    const int t    = threadIdx.x;
    const int lane = t & 63;
    const int wav  = t >> 6;
    const float4* xg = (const float4*)x + (size_t)blk * TILE_F4;

#pragma unroll
    for (int i = 0; i < VLMAX; ++i) {
        int idx = t + NTHREADS * i;
        if (idx < TILE_F4) gload_lds16(xg + idx, &tile[idx]);
    }
    __syncthreads();

    // Thread t owns words 22t..22t+21 (timesteps 2t,2t+1). Word 22t+k has
    // feature k%11 (22t === 0 mod 11). float2 #m -> features (2m)%11,(2m+1)%11.
    const float2* lds2 = (const float2*)tile;
    float s[FEAT];
#pragma unroll
    for (int f = 0; f < FEAT; ++f) s[f] = 0.0f;
#pragma unroll
    for (int m = 0; m < FEAT; ++m) {
        float2 q = lds2[FEAT * t + m];
        s[(2 * m) % FEAT]     += q.x;
        s[(2 * m + 1) % FEAT] += q.y;
    }
#pragma unroll
    for (int f = 0; f < FEAT; ++f) s[f] = wave_iscan(s[f]);  // lane63 = total
    if (lane == 63) {
#pragma unroll
        for (int f = 0; f < FEAT; ++f) waveSum[wav][f] = s[f];
    }
    __syncthreads();
    if (t < FEAT) {
        float p = waveSum[0][t] + waveSum[1][t] + waveSum[2][t] + waveSum[3][t];
        partials[(size_t)blk * FEAT + t] = p;
    }
}

// ---------------- Kernel C: scan each chunk with known offset ----------------
__global__ __launch_bounds__(NTHREADS, 8)
void scan_kernel(const float* __restrict__ x,
                 const float* __restrict__ init_state,
                 const float* __restrict__ partials,
                 float* __restrict__ y) {
    __shared__ float4 tile[TILE_F4];          // 22,528 B
    __shared__ float  waveTot[NWAVE][FEAT];
    __shared__ float  offsh[FEAT];

    const int blk  = blockIdx.x;
    const int b    = blk >> 3;                // NC = 8
    const int c    = blk & (NC - 1);
    const int t    = threadIdx.x;
    const int lane = t & 63;
    const int wav  = t >> 6;

    const float4* xg = (const float4*)x + (size_t)blk * TILE_F4;
    float4*       yg = (float4*)y + (size_t)blk * TILE_F4;
    const float init_v = init_state[b];

#pragma unroll
    for (int i = 0; i < VLMAX; ++i) {
        int idx = t + NTHREADS * i;
        if (idx < TILE_F4) gload_lds16(xg + idx, &tile[idx]);
    }
    // chunk offset = sum of preceding chunks' partials (loads issued
    // unconditionally for ILP; all addresses valid, predicated accumulate)
    if (t < FEAT) {
        float o = 0.0f;
#pragma unroll
        for (int cc = 0; cc < NC - 1; ++cc) {
            float pv = partials[(size_t)(b * NC + cc) * FEAT + t];
            if (cc < c) o += pv;
        }
        offsh[t] = o;
    }
    __syncthreads();

    // transpose read: float2 index 11t+m -> word 22t+2m; stride 22,
    // gcd(22,32)=2 -> 2 lanes/bank = free.
    const float2* lds2 = (const float2*)tile;
    float L[2 * FEAT];
#pragma unroll
    for (int m = 0; m < FEAT; ++m) {
        float2 q = lds2[FEAT * t + m];
        L[2 * m]     = q.x;
        L[2 * m + 1] = q.y;
    }
    // local prefix over own 2 steps + wave scan of totals
    float inc[FEAT];
#pragma unroll
    for (int f = 0; f < FEAT; ++f) {
        L[FEAT + f] += L[f];
        inc[f] = wave_iscan(L[FEAT + f]);
    }
    if (lane == 63) {
#pragma unroll
        for (int f = 0; f < FEAT; ++f) waveTot[wav][f] = inc[f];
    }
    __syncthreads();

    // epilogue: global offset + cross-wave exclusive + wave-exclusive
    float2* ldsw = (float2*)tile;
#pragma unroll
    for (int f = 0; f < FEAT; ++f) {
        float off = offsh[f] + inc[f] - L[FEAT + f];   // exclusive in wave
#pragma unroll
        for (int w = 0; w < NWAVE; ++w)
            if (w < wav) off += waveTot[w][f];
        L[f]        = init_v + FACTOR * (off + L[f]);
        L[FEAT + f] = init_v + FACTOR * (off + L[FEAT + f]);
    }
#pragma unroll
    for (int m = 0; m < FEAT; ++m)
        ldsw[FEAT * t + m] = make_float2(L[2 * m], L[2 * m + 1]);
    __syncthreads();

    // coalesced float4 store
#pragma unroll
    for (int i = 0; i < VLMAX; ++i) {
        int idx = t + NTHREADS * i;
        if (idx < TILE_F4) yg[idx] = tile[idx];
    }
}

extern "C" void kernel_launch(void* const* d_in, const int* in_sizes, int n_in,
                              void* d_out, int out_size, void* d_ws, size_t ws_size,
                              hipStream_t stream) {
    const float* x    = (const float*)d_in[0];
    const float* init = (const float*)d_in[1];
    float*       y    = (float*)d_out;
    float*       part = (float*)d_ws;         // 8192*11*4 = 360,448 B
    partial_kernel<<<dim3(NBLK), dim3(NTHREADS), 0, stream>>>(x, part);
    scan_kernel<<<dim3(NBLK), dim3(NTHREADS), 0, stream>>>(x, init, part, y);
}